// Round 3
// baseline (654.226 us; speedup 1.0000x reference)
//
#include <hip/hip_runtime.h>

// Com2Net wavefront kernel, round 6: two waves per run on two SIMDs.
// R5 post-mortem nailed the model: issue = 53 non-trans x 2cyc + 15 trans x
// 16cyc = 346/eval, 692/step predicted vs 690 measured (VALUBusy back-solve).
// 70% of the SIMD's cycles are issue, 70% of issue is transcendental (exp2/rcp
// at wave64 quarter rate) -> the kernel is bound by ONE SIMD's trans+issue
// bandwidth. Fix: split the 10 hidden pairs of each macro-step across 2 waves
// (wave0: even{0,1,2}+odd{0,1}; wave1: even{3,4}+odd{2,3,4}), replicate the
// c-state in both waves, and exchange 3 partial-dot scalars per lane per phase
// through LDS. Replicas stay bitwise identical (a+b==b+a in IEEE; same selects).
// Sync: raw s_barrier with lgkmcnt(0) ONLY (no vmcnt drain -> the distance-4
// global prefetch stays in flight across barriers). Double-buffered exchange
// (even->buf0, odd->buf1) makes one barrier per phase race-free.

#define T_STEPS 1024
#define N_AGENTS 128

typedef float v2f __attribute__((ext_vector_type(2)));

__device__ __forceinline__ v2f sp(float x) { return (v2f){x, x}; }

// Whole-wave shift-by-1 via DPP. wave_shr1 (0x138): lane i <- lane i-1,
// lane 0 <- 0 (bound_ctrl). wave_shl1 (0x130): lane i <- lane i+1, lane 63 <- 0.
// bound_ctrl zeros are exactly comm[0]/comm[2N+1], which are never written.
__device__ __forceinline__ float wave_shr1(float x) {
    int r = __builtin_amdgcn_update_dpp(0, __builtin_bit_cast(int, x),
                                        0x138, 0xF, 0xF, true);
    return __builtin_bit_cast(float, r);
}
__device__ __forceinline__ float wave_shl1(float x) {
    int r = __builtin_amdgcn_update_dpp(0, __builtin_bit_cast(int, x),
                                        0x130, 0xF, 0xF, true);
    return __builtin_bit_cast(float, r);
}

struct Weights {
    v2f w1x0[5], w1x1[5];    // layer-1 x weights (cols 0,1), * 2*log2(e)
    v2f w1cA[5], w1cB[5];    // layer-1 comm weights (cols 2,3), * 2*log2(e)
    v2f b1[5];               // * 2*log2(e)
    v2f w20[5], w21[5], w22[5];  // = -2 * W2 row r, packed over hidden pairs
    float b20, b21, b22;         // = b2[r] + sum_k W2[r,k]
};

// Partial S2Net eval over hidden pairs [P0,P1). Bias included iff P0==0
// (wave0 always owns pair 0 -> bias counted exactly once).
// sigma = B*rcp(A*B)/A*rcp(A*B) pairing; tanh affine folded into w2*/b2*.
template<int P0, int P1>
__device__ __forceinline__ void eval_part(const Weights& w, float xa, float xb,
                                          float cA, float cB,
                                          float& s0, float& s1, float& s2) {
    v2f h[P1 - P0];
#pragma unroll
    for (int p = P0; p < P1; ++p) {
        v2f a = __builtin_elementwise_fma(w.w1x0[p], sp(xa), w.b1[p]);
        a = __builtin_elementwise_fma(w.w1x1[p], sp(xb), a);
        a = __builtin_elementwise_fma(w.w1cB[p], sp(cB), a);
        a = __builtin_elementwise_fma(w.w1cA[p], sp(cA), a);
        v2f t;
        t.x = __builtin_amdgcn_exp2f(a.x);
        t.y = __builtin_amdgcn_exp2f(a.y);
        t = t + (v2f){1.f, 1.f};              // A = 1+2^a, B = 1+2^b
        float rr = __builtin_amdgcn_rcpf(t.x * t.y);
        h[p - P0] = (v2f){t.y, t.x} * sp(rr); // {sigma(a), sigma(b)}
    }
    v2f a0, a1, a2;
    if constexpr (P0 == 0) {
        a0 = (v2f){w.b20, 0.f}; a1 = (v2f){w.b21, 0.f}; a2 = (v2f){w.b22, 0.f};
    } else {
        a0 = (v2f){0.f, 0.f}; a1 = (v2f){0.f, 0.f}; a2 = (v2f){0.f, 0.f};
    }
#pragma unroll
    for (int p = P0; p < P1; ++p) {
        a0 = __builtin_elementwise_fma(w.w20[p], h[p - P0], a0);
        a1 = __builtin_elementwise_fma(w.w21[p], h[p - P0], a1);
        a2 = __builtin_elementwise_fma(w.w22[p], h[p - P0], a2);
    }
    s0 = a0.x + a0.y; s1 = a1.x + a1.y; s2 = a2.x + a2.y;
}

__global__ void __launch_bounds__(128, 1)
com2net_wavefront(const float* __restrict__ runs,
                  const float* __restrict__ W1, const float* __restrict__ b1,
                  const float* __restrict__ W2, const float* __restrict__ b2,
                  float* __restrict__ out)
{
    const int r   = blockIdx.x;          // run index
    const int j   = threadIdx.x & 63;    // lane, owns agents 2j and 2j+1
    const int wid = threadIdx.x >> 6;    // wave 0/1 (different SIMDs)

    // Partial-dot exchange: [buf][output k][wave][lane]. Conflict-free b32
    // (lane j -> bank j%32). 3 KiB total.
    __shared__ float xch[2][3][2][64];

    const float S = 2.8853900817779268f;  // 2*log2(e), folded into layer 1
    Weights w;
#pragma unroll
    for (int p = 0; p < 5; ++p) {
        w.b1[p]   = (v2f){b1[2 * p] * S, b1[2 * p + 1] * S};
        w.w1x0[p] = (v2f){W1[(2 * p) * 4 + 0] * S, W1[(2 * p + 1) * 4 + 0] * S};
        w.w1x1[p] = (v2f){W1[(2 * p) * 4 + 1] * S, W1[(2 * p + 1) * 4 + 1] * S};
        w.w1cA[p] = (v2f){W1[(2 * p) * 4 + 2] * S, W1[(2 * p + 1) * 4 + 2] * S};
        w.w1cB[p] = (v2f){W1[(2 * p) * 4 + 3] * S, W1[(2 * p + 1) * 4 + 3] * S};
        w.w20[p] = (v2f){-2.f * W2[0 * 10 + 2 * p], -2.f * W2[0 * 10 + 2 * p + 1]};
        w.w21[p] = (v2f){-2.f * W2[1 * 10 + 2 * p], -2.f * W2[1 * 10 + 2 * p + 1]};
        w.w22[p] = (v2f){-2.f * W2[2 * 10 + 2 * p], -2.f * W2[2 * 10 + 2 * p + 1]};
    }
    float s0w = 0.f, s1w = 0.f, s2w = 0.f;
#pragma unroll
    for (int k = 0; k < 10; ++k) {
        s0w += W2[0 * 10 + k];
        s1w += W2[1 * 10 + k];
        s2w += W2[2 * 10 + k];
    }
    w.b20 = b2[0] + s0w; w.b21 = b2[1] + s1w; w.b22 = b2[2] + s2w;

    const float4* __restrict__ xbase =
        (const float4*)(runs + (size_t)r * T_STEPS * N_AGENTS * 2);
    float2* __restrict__ obase =
        (float2*)(out + (size_t)r * T_STEPS * N_AGENTS);

    // Replicated recurrence state (identical in both waves at all times).
    float c1e = 0.f, c2e = 0.f, c1o = 0.f, c2o = 0.f;

    // Barrier with LDS-only drain: lgkmcnt(0) makes our ds_writes visible;
    // vmcnt NOT drained so the global prefetch pipeline survives the barrier.
    auto xbar = [] {
        asm volatile("s_waitcnt lgkmcnt(0)" ::: "memory");
        __builtin_amdgcn_s_barrier();
        asm volatile("" ::: "memory");
    };

    // One phase: each wave computes its pair-subset partial dots, exchanges
    // 3 scalars, both waves form the identical full sums.
    auto phaseE = [&](float xa, float xb, float cA, float cB,
                      float& o0, float& o1, float& o2) {
        float s0, s1, s2;
        if (wid == 0) eval_part<0, 3>(w, xa, xb, cA, cB, s0, s1, s2);
        else          eval_part<3, 5>(w, xa, xb, cA, cB, s0, s1, s2);
        xch[0][0][wid][j] = s0;
        xch[0][1][wid][j] = s1;
        xch[0][2][wid][j] = s2;
        xbar();
        o0 = s0 + xch[0][0][wid ^ 1][j];
        o1 = s1 + xch[0][1][wid ^ 1][j];
        o2 = s2 + xch[0][2][wid ^ 1][j];
    };
    auto phaseO = [&](float xa, float xb, float cA, float cB,
                      float& o0, float& o1, float& o2) {
        float s0, s1, s2;
        if (wid == 0) eval_part<0, 2>(w, xa, xb, cA, cB, s0, s1, s2);
        else          eval_part<2, 5>(w, xa, xb, cA, cB, s0, s1, s2);
        xch[1][0][wid][j] = s0;
        xch[1][1][wid][j] = s1;
        xch[1][2][wid][j] = s2;
        xbar();
        o0 = s0 + xch[1][0][wid ^ 1][j];
        o1 = s1 + xch[1][1][wid ^ 1][j];
        o2 = s2 + xch[1][2][wid ^ 1][j];
    };

    // Clamped row load for ramp/tail (OOB lanes re-read row 0/1023; results
    // discarded by the activity selects, loads hit cache).
    auto ldrow = [&](int t) -> float4 {
        int tc = t < 0 ? 0 : t;
        tc = tc > T_STEPS - 1 ? T_STEPS - 1 : tc;
        return xbase[tc * (N_AGENTS / 2) + j];
    };
    auto ldrow_fast = [&](int t) -> float4 {
        return xbase[t * (N_AGENTS / 2) + j];
    };

    // General step (ramp/tail): activity selects + predicated store.
    // `active` depends on j only -> identical in both waves -> replicas agree.
    auto step_gen = [&](int u, const float4& x) {
        const int t = u - j;
        const bool active = (unsigned)t < (unsigned)T_STEPS;

        float c2pv = wave_shr1(c2o);
        float o0e, o1e, o2e;
        phaseE(x.x, x.y, c2pv, c1o, o0e, o1e, o2e);
        c1e = active ? o1e : c1e;
        c2e = active ? o2e : c2e;

        float c1pv = wave_shl1(c1e);
        float o0o, o1o, o2o;
        phaseO(x.z, x.w, c2e, c1pv, o0o, o1o, o2o);
        c1o = active ? o1o : c1o;
        c2o = active ? o2o : c2o;

        if (wid == 0 && active)
            obase[t * (N_AGENTS / 2) + j] = make_float2(o0e, o0o);
    };

    // Steady step: all lanes active, no selects, unconditional store (wave0).
    auto step_fast = [&](int u, const float4& x) {
        const int t = u - j;
        float c2pv = wave_shr1(c2o);
        float o0e, o1e, o2e;
        phaseE(x.x, x.y, c2pv, c1o, o0e, o1e, o2e);
        c1e = o1e; c2e = o2e;
        float c1pv = wave_shl1(c1e);
        float o0o, o1o, o2o;
        phaseO(x.z, x.w, c2e, c1pv, o0o, o1o, o2o);
        c1o = o1o; c2o = o2o;
        if (wid == 0)
            obase[t * (N_AGENTS / 2) + j] = make_float2(o0e, o0o);
    };

    // Distance-4 register prefetch pipeline, manual unroll-by-4.
    float4 X0 = ldrow(0 - j);
    float4 X1 = ldrow(1 - j);
    float4 X2 = ldrow(2 - j);
    float4 X3 = ldrow(3 - j);

    // Ramp: u in [0,64). Some lanes inactive (t<0); clamped prefetch.
    for (int u = 0; u < 64; u += 4) {
        step_gen(u + 0, X0); X0 = ldrow(u + 4 - j);
        step_gen(u + 1, X1); X1 = ldrow(u + 5 - j);
        step_gen(u + 2, X2); X2 = ldrow(u + 6 - j);
        step_gen(u + 3, X3); X3 = ldrow(u + 7 - j);
    }
    // Steady: u in [64,1012). All lanes active; prefetch t in [0,1023].
    for (int u = 64; u < 1012; u += 4) {
        step_fast(u + 0, X0); X0 = ldrow_fast(u + 4 - j);
        step_fast(u + 1, X1); X1 = ldrow_fast(u + 5 - j);
        step_fast(u + 2, X2); X2 = ldrow_fast(u + 6 - j);
        step_fast(u + 3, X3); X3 = ldrow_fast(u + 7 - j);
    }
    // Tail: u in [1012,1088). Lanes with t>1023 inactive; clamped prefetch.
    for (int u = 1012; u < 1088; u += 4) {
        step_gen(u + 0, X0); X0 = ldrow(u + 4 - j);
        step_gen(u + 1, X1); X1 = ldrow(u + 5 - j);
        step_gen(u + 2, X2); X2 = ldrow(u + 6 - j);
        step_gen(u + 3, X3); X3 = ldrow(u + 7 - j);
    }
}

extern "C" void kernel_launch(void* const* d_in, const int* in_sizes, int n_in,
                              void* d_out, int out_size, void* d_ws, size_t ws_size,
                              hipStream_t stream) {
    const float* runs = (const float*)d_in[0];
    const float* W1   = (const float*)d_in[1];
    const float* b1   = (const float*)d_in[2];
    const float* W2   = (const float*)d_in[3];
    const float* b2   = (const float*)d_in[4];
    float* out = (float*)d_out;

    const int R = 128;
    com2net_wavefront<<<R, 128, 0, stream>>>(runs, W1, b1, W2, b2, out);
}

// Round 4
// 551.346 us; speedup vs baseline: 1.1866x; 1.1866x over previous
//
#include <hip/hip_runtime.h>

// Com2Net wavefront kernel, round 7.
// Schedule s = 2t + i; ONE wave per run (R6 proved cross-SIMD splits dead:
// LDS hop ~200-250cyc on the serial chain >= issue offloaded ~170/phase;
// per-run step latency IS the kernel time).
// Best-known: R3 = 956 cyc/step (issue ~780, stall ~175). R5 cut issue to 690
// but paired-rcp's cross-element chain pushed stall to 298 (net loss).
// This round = R3's exact loop/schedule + sigma-fold ONLY:
//   - sigma-fold (numerically verified in R4/R5): W2@tanh = (W2@1+b2) +
//     (-2*W2)@sigma, sigma = rcp(1+exp2(a)), scale folded into layer 1.
//     Deletes the (1-2r) glue pk_fma per hidden pair (-10 instr/step).
//   - per-element rcp (NOT paired): shortest sigma chain, no half-swap.
//   - single general loop (R3 shape), distance-4 prefetch, min/max clamp.

#define T_STEPS 1024
#define N_AGENTS 128

typedef float v2f __attribute__((ext_vector_type(2)));

__device__ __forceinline__ v2f sp(float x) { return (v2f){x, x}; }

// Whole-wave shift-by-1 via DPP. wave_shr1 (0x138): lane i <- lane i-1,
// lane 0 <- 0 (bound_ctrl). wave_shl1 (0x130): lane i <- lane i+1, lane 63 <- 0.
// bound_ctrl zeros are exactly comm[0]/comm[2N+1], which are never written.
__device__ __forceinline__ float wave_shr1(float x) {
    int r = __builtin_amdgcn_update_dpp(0, __builtin_bit_cast(int, x),
                                        0x138, 0xF, 0xF, true);
    return __builtin_bit_cast(float, r);
}
__device__ __forceinline__ float wave_shl1(float x) {
    int r = __builtin_amdgcn_update_dpp(0, __builtin_bit_cast(int, x),
                                        0x130, 0xF, 0xF, true);
    return __builtin_bit_cast(float, r);
}

struct Weights {
    v2f w1x0[5], w1x1[5];    // layer-1 x weights (cols 0,1), * 2*log2(e)
    v2f w1cA[5], w1cB[5];    // layer-1 comm weights (cols 2,3), * 2*log2(e)
    v2f b1[5];               // * 2*log2(e)
    v2f w20[5], w21[5], w22[5];  // = -2 * W2 row r, packed over hidden pairs
    float b20, b21, b22;         // = b2[r] + sum_k W2[r,k]
};

// One S2Net eval, fused (x fmas lead so the scheduler can hoist them into
// the previous phase's stall gaps; cA/cB are the chain-late operands).
// h = sigma = rcp(1 + exp2(a)) per element; tanh affine folded into w2*/b2*.
__device__ __forceinline__ void mlp_eval(const Weights& w, float xa, float xb,
                                         float cA, float cB,
                                         float& o0, float& o1, float& o2) {
    v2f h[5];
#pragma unroll
    for (int p = 0; p < 5; ++p) {
        v2f a = __builtin_elementwise_fma(w.w1x0[p], sp(xa), w.b1[p]);
        a = __builtin_elementwise_fma(w.w1x1[p], sp(xb), a);
        a = __builtin_elementwise_fma(w.w1cB[p], sp(cB), a);
        a = __builtin_elementwise_fma(w.w1cA[p], sp(cA), a);
        v2f t;
        t.x = __builtin_amdgcn_exp2f(a.x);
        t.y = __builtin_amdgcn_exp2f(a.y);
        t = t + (v2f){1.f, 1.f};
        h[p].x = __builtin_amdgcn_rcpf(t.x);
        h[p].y = __builtin_amdgcn_rcpf(t.y);
    }
    // Output dots packed over hidden dim; horizontal add folds the pair.
    v2f a0 = __builtin_elementwise_fma(w.w20[0], h[0], (v2f){w.b20, 0.f});
    v2f a1 = __builtin_elementwise_fma(w.w21[0], h[0], (v2f){w.b21, 0.f});
    v2f a2 = __builtin_elementwise_fma(w.w22[0], h[0], (v2f){w.b22, 0.f});
#pragma unroll
    for (int p = 1; p < 5; ++p) {
        a0 = __builtin_elementwise_fma(w.w20[p], h[p], a0);
        a1 = __builtin_elementwise_fma(w.w21[p], h[p], a1);
        a2 = __builtin_elementwise_fma(w.w22[p], h[p], a2);
    }
    o0 = a0.x + a0.y;
    o1 = a1.x + a1.y;
    o2 = a2.x + a2.y;
}

__global__ void __launch_bounds__(64, 1)
com2net_wavefront(const float* __restrict__ runs,
                  const float* __restrict__ W1, const float* __restrict__ b1,
                  const float* __restrict__ W2, const float* __restrict__ b2,
                  float* __restrict__ out)
{
    const int r = blockIdx.x;   // run index
    const int j = threadIdx.x;  // lane 0..63, owns agents 2j and 2j+1

    const float S = 2.8853900817779268f;  // 2*log2(e), folded into layer 1
    Weights w;
#pragma unroll
    for (int p = 0; p < 5; ++p) {
        w.b1[p]   = (v2f){b1[2 * p] * S, b1[2 * p + 1] * S};
        w.w1x0[p] = (v2f){W1[(2 * p) * 4 + 0] * S, W1[(2 * p + 1) * 4 + 0] * S};
        w.w1x1[p] = (v2f){W1[(2 * p) * 4 + 1] * S, W1[(2 * p + 1) * 4 + 1] * S};
        w.w1cA[p] = (v2f){W1[(2 * p) * 4 + 2] * S, W1[(2 * p + 1) * 4 + 2] * S};
        w.w1cB[p] = (v2f){W1[(2 * p) * 4 + 3] * S, W1[(2 * p + 1) * 4 + 3] * S};
        w.w20[p] = (v2f){-2.f * W2[0 * 10 + 2 * p], -2.f * W2[0 * 10 + 2 * p + 1]};
        w.w21[p] = (v2f){-2.f * W2[1 * 10 + 2 * p], -2.f * W2[1 * 10 + 2 * p + 1]};
        w.w22[p] = (v2f){-2.f * W2[2 * 10 + 2 * p], -2.f * W2[2 * 10 + 2 * p + 1]};
    }
    float s0 = 0.f, s1 = 0.f, s2 = 0.f;
#pragma unroll
    for (int k = 0; k < 10; ++k) {
        s0 += W2[0 * 10 + k];
        s1 += W2[1 * 10 + k];
        s2 += W2[2 * 10 + k];
    }
    w.b20 = b2[0] + s0; w.b21 = b2[1] + s1; w.b22 = b2[2] + s2;

    const float4* __restrict__ xbase =
        (const float4*)(runs + (size_t)r * T_STEPS * N_AGENTS * 2);
    float2* __restrict__ obase =
        (float2*)(out + (size_t)r * T_STEPS * N_AGENTS);

    // c1*/c2* = out1/out2 of this lane's even/odd agent at its latest t.
    // Zero-init == initial comm; inactive lanes never update -> t<0 boundary.
    float c1e = 0.f, c2e = 0.f, c1o = 0.f, c2o = 0.f;

    // Clamped row load (OOB lanes re-read row 0/1023; results are discarded
    // by the activity selects, loads hit cache).
    auto ldrow = [&](int t) -> float4 {
        int tc = t < 0 ? 0 : t;
        tc = tc > T_STEPS - 1 ? T_STEPS - 1 : tc;
        return xbase[tc * (N_AGENTS / 2) + j];
    };

    auto step = [&](int u, const float4& x) {
        const int t = u - j;
        const bool active = (unsigned)t < (unsigned)T_STEPS;

        // ---- even phase: agent 2j at t ----
        // comm[4j]   = lane j-1's c2o (prev macro-step) -> wave_shr1
        // comm[4j+3] = own c1o (prev macro-step)
        float c2pv = wave_shr1(c2o);
        float o0e, o1e, o2e;
        mlp_eval(w, x.x, x.y, c2pv, c1o, o0e, o1e, o2e);
        c1e = active ? o1e : c1e;
        c2e = active ? o2e : c2e;

        // ---- odd phase: agent 2j+1 at t ----
        // comm[4j+2] = own c2e (just computed)
        // comm[4j+5] = lane j+1's c1e (its even phase this step ran at t-1)
        float c1pv = wave_shl1(c1e);
        float o0o, o1o, o2o;
        mlp_eval(w, x.z, x.w, c2e, c1pv, o0o, o1o, o2o);
        c1o = active ? o1o : c1o;
        c2o = active ? o2o : c2o;

        if (active) obase[t * (N_AGENTS / 2) + j] = make_float2(o0e, o0o);
    };

    // Distance-4 register prefetch pipeline, manual unroll-by-4 (R3 shape).
    float4 X0 = ldrow(0 - j);
    float4 X1 = ldrow(1 - j);
    float4 X2 = ldrow(2 - j);
    float4 X3 = ldrow(3 - j);

    for (int u = 0; u < T_STEPS + 64; u += 4) {   // 1088 = 4*272 iters
        step(u + 0, X0); X0 = ldrow(u + 4 - j);
        step(u + 1, X1); X1 = ldrow(u + 5 - j);
        step(u + 2, X2); X2 = ldrow(u + 6 - j);
        step(u + 3, X3); X3 = ldrow(u + 7 - j);
    }
}

extern "C" void kernel_launch(void* const* d_in, const int* in_sizes, int n_in,
                              void* d_out, int out_size, void* d_ws, size_t ws_size,
                              hipStream_t stream) {
    const float* runs = (const float*)d_in[0];
    const float* W1   = (const float*)d_in[1];
    const float* b1   = (const float*)d_in[2];
    const float* W2   = (const float*)d_in[3];
    const float* b2   = (const float*)d_in[4];
    float* out = (float*)d_out;

    const int R = 128;
    com2net_wavefront<<<R, 64, 0, stream>>>(runs, W1, b1, W2, b2, out);
}